// Round 10
// baseline (401.912 us; speedup 1.0000x reference)
//
#include <hip/hip_runtime.h>

#define N_NODES 50000
#define N_EDGES 800000
#define IN_DIM 32
#define HD 256   // H*D
#define H_ 8
#define D_ 32
#define ECAP 64  // edges stashed in LDS per node (recompute tail beyond)
#define NT 17    // 16 W1 col-tiles + 1 Wa1 tile (el/er)

typedef __attribute__((ext_vector_type(8))) short bf16x8;
typedef __attribute__((ext_vector_type(4))) float f32x4;
typedef __attribute__((ext_vector_type(8))) unsigned short u16x8;

__device__ inline unsigned short f2b(float f){
  union{float f;unsigned int u;}v; v.f=f;
  unsigned int r=(v.u + 0x7FFFu + ((v.u>>16)&1u))>>16;
  return (unsigned short)r;
}
__device__ inline float b2f(unsigned short u){
  union{float f;unsigned int u32;}v; v.u32=((unsigned int)u)<<16; return v.f;
}

// ---------------- CSR build ----------------

__global__ void k_hist(const int* __restrict__ dst, int* __restrict__ deg){
  int e = blockIdx.x*256+threadIdx.x;
  if (e < N_EDGES) atomicAdd(&deg[dst[e]], 1);
}

__global__ void k_block_sums(const int* __restrict__ deg, int* __restrict__ bsums){
  int i = blockIdx.x*256+threadIdx.x;
  int v = (i<N_NODES)? deg[i]:0;
  #pragma unroll
  for (int o=32;o>=1;o>>=1) v += __shfl_xor(v,o,64);
  __shared__ int ws[4];
  if ((threadIdx.x&63)==0) ws[threadIdx.x>>6]=v;
  __syncthreads();
  if (threadIdx.x==0) bsums[blockIdx.x]=ws[0]+ws[1]+ws[2]+ws[3];
}

__global__ void k_scan_bsums(int* bsums, int nb){
  if (threadIdx.x==0 && blockIdx.x==0){
    int a=0;
    for (int i=0;i<nb;i++){int t=bsums[i]; bsums[i]=a; a+=t;}
  }
}

__device__ inline int wave_incl_scan(int v){
  int lane = threadIdx.x & 63;
  #pragma unroll
  for (int o=1;o<64;o<<=1){
    int t = __shfl_up(v,o,64);
    if (lane>=o) v+=t;
  }
  return v;
}

__global__ void k_scan_chunks(const int* __restrict__ deg, const int* __restrict__ bsums,
                              int* __restrict__ offs, int* __restrict__ cursor){
  int i = blockIdx.x*256+threadIdx.x;
  int v = (i<N_NODES)? deg[i]:0;
  int incl = wave_incl_scan(v);
  __shared__ int ws[4];
  int wid=threadIdx.x>>6, lane=threadIdx.x&63;
  if (lane==63) ws[wid]=incl;
  __syncthreads();
  if (threadIdx.x==0){int a=0; for(int w=0;w<4;w++){int t=ws[w];ws[w]=a;a+=t;}}
  __syncthreads();
  int excl = incl - v + ws[wid] + bsums[blockIdx.x];
  if (i<N_NODES){ offs[i]=excl; cursor[i]=excl; }
  if (i==N_NODES-1) offs[N_NODES]=excl+v;
}

__global__ void k_scatter(const int* __restrict__ src, const int* __restrict__ dst,
                          int* __restrict__ cursor, int* __restrict__ csr_src,
                          int* __restrict__ csr_eid){
  int e = blockIdx.x*256+threadIdx.x;
  if (e<N_EDGES){
    int d = dst[e];
    int pos = atomicAdd(&cursor[d],1);
    csr_src[pos]=src[e];
    csr_eid[pos]=e;
  }
}

// ---------------- Wa precompute ----------------

template<int K>
__global__ void k_prep(const float* __restrict__ W, const float* __restrict__ al,
                       const float* __restrict__ ar, float* __restrict__ Wa){
  int t = blockIdx.x*256 + threadIdx.x;
  int k = t>>3, hh = t&7;
  if (k < K){
    float sl=0.f, sr=0.f;
    #pragma unroll
    for (int d=0; d<32; d++){
      float w = W[(size_t)k*HD + hh*32 + d];
      sl = fmaf(w, al[hh*32+d], sl);
      sr = fmaf(w, ar[hh*32+d], sr);
    }
    Wa[k*16 + hh]     = sl;
    Wa[k*16 + 8 + hh] = sr;
  }
}

// ---------------- fragment pack: 16 tiles of W1 + 1 tile of Wa1 ----------------

__global__ void k_pack_w(const float* __restrict__ W, const float* __restrict__ Wa1,
                         unsigned short* __restrict__ Wp){
  int t = blockIdx.x*256+threadIdx.x;   // 8*NT*64*8 = 69632 total
  if (t >= 8*NT*64*8) return;
  int j=t&7, lane=(t>>3)&63;
  int g=t>>9; int nt=g%NT, ks=g/NT;
  int k = ks*32 + (lane>>4)*8 + j;
  float v;
  if (nt<16) v = W[(size_t)k*HD + nt*16 + (lane&15)];
  else       v = Wa1[k*16 + (lane&15)];
  Wp[t] = f2b(v);
}

// ---------------- W0 pack (bf16, k-major per col) ----------------

__global__ void k_pack_w0(const float* __restrict__ W0, unsigned short* __restrict__ W0t){
  int t = blockIdx.x*256+threadIdx.x;   // 8192 total
  if (t < 8192){
    int q = t&7, c = (t>>3)&255, kb = t>>11;
    W0t[t] = f2b(W0[(size_t)(kb*8+q)*HD + c]);
  }
}

// ---------------- el/er (layer 0) + bf16 copy of x ----------------

__global__ __launch_bounds__(256) void k_el0(const float* __restrict__ x, const float* __restrict__ Wa,
                                             float* __restrict__ elr, unsigned short* __restrict__ xb){
  __shared__ float sWa[IN_DIM*16];
  __shared__ float sx[16][IN_DIM+1];
  int tid = threadIdx.x;
  int nb = blockIdx.x*16;
  for (int i = tid; i < IN_DIM*16; i += 256) sWa[i] = Wa[i];
  for (int i = tid; i < 16*IN_DIM; i += 256){
    int r = i >> 5, c = i & 31;
    sx[r][c] = x[(size_t)(nb+r)*IN_DIM + c];
  }
  __syncthreads();
  int node = tid>>4, j = tid&15;
  float s = 0.f;
  #pragma unroll 8
  for (int k=0;k<IN_DIM;k++) s = fmaf(sx[node][k], sWa[k*16+j], s);
  elr[(size_t)(nb+node)*16 + j] = s;
  for (int i = tid; i < 16*IN_DIM; i += 256){
    int r = i >> 5, c = i & 31;
    xb[(size_t)(nb+r)*IN_DIM + c] = f2b(sx[r][c]);
  }
}

// ---------------- FUSED layer-0 (bf16 x gather) ----------------

__global__ __launch_bounds__(256) void k_agg0f(const int* __restrict__ offs, const int* __restrict__ csr_src,
    const unsigned short* __restrict__ xb, const float* __restrict__ elr,
    const unsigned short* __restrict__ W0t, const float* __restrict__ b0,
    unsigned short* __restrict__ h1b){
  __shared__ float s_al[4][ECAP][H_];
  __shared__ int   s_sn[4][ECAP];
  __shared__ float s_m[4][H_], s_is[4][H_];
  __shared__ float s_hg[4][32*9];      // transposed hagg, stride 9 (bank-spread)
  int w = threadIdx.x>>6, lane = threadIdx.x&63;
  int n = blockIdx.x*4 + w;
  int h = lane>>3, sub = lane&7;
  int off = offs[n], deg = offs[n+1]-off;
  float er_n = elr[n*16 + 8 + h];

  // ---- phase A: scores -> LDS, online (m,s) ----
  float m=-1e30f, s=0.f;
  for (int i=sub; i<deg; i+=8){
    int sn = csr_src[off+i];
    float sc = elr[sn*16+h] + er_n;
    sc = sc>0.f? sc : 0.2f*sc;
    if (i<ECAP){ s_al[w][i][h] = sc; if (h==0) s_sn[w][i] = sn; }
    float mn = fmaxf(m,sc);
    s = s*__expf(m-mn) + __expf(sc-mn);
    m = mn;
  }
  #pragma unroll
  for (int o=4;o>=1;o>>=1){
    float m2=__shfl_xor(m,o,64), s2=__shfl_xor(s,o,64);
    float mn=fmaxf(m,m2);
    s = s*__expf(m-mn)+s2*__expf(m2-mn); m=mn;
  }
  float inv_s = (s>0.f)?1.f/s:0.f;
  if (sub==0){ s_m[w][h]=m; s_is[w][h]=inv_s; }
  int dcap = deg<ECAP? deg:ECAP;
  int dcap_pad = (dcap+15)&~15;
  for (int i=sub; i<dcap; i+=8)
    s_al[w][i][h] = __expf(s_al[w][i][h]-m)*inv_s;
  for (int i=dcap+lane; i<dcap_pad; i+=64){   // pad to 16-boundary: zero-alpha dummy edges
    s_sn[w][i]=0;
    *(float4*)&s_al[w][i][0]=make_float4(0,0,0,0);
    *(float4*)&s_al[w][i][4]=make_float4(0,0,0,0);
  }
  __syncthreads();

  // ---- phase B: tail-free 16-edge chunks, bf16 x (per-XCD L2-resident) ----
  int hw = lane>>5, d = lane&31;
  float acc[H_]  = {0,0,0,0,0,0,0,0};
  int i = hw;
  for (; i<dcap_pad; i+=16){
    float xv[8];
    #pragma unroll
    for (int q=0;q<8;q++)
      xv[q] = b2f(xb[(size_t)s_sn[w][i+2*q]*IN_DIM + d]);
    #pragma unroll
    for (int q=0;q<8;q++){
      float4 a0 = *(const float4*)&s_al[w][i+2*q][0];
      float4 a1 = *(const float4*)&s_al[w][i+2*q][4];
      acc[0]=fmaf(a0.x,xv[q],acc[0]); acc[1]=fmaf(a0.y,xv[q],acc[1]);
      acc[2]=fmaf(a0.z,xv[q],acc[2]); acc[3]=fmaf(a0.w,xv[q],acc[3]);
      acc[4]=fmaf(a1.x,xv[q],acc[4]); acc[5]=fmaf(a1.y,xv[q],acc[5]);
      acc[6]=fmaf(a1.z,xv[q],acc[6]); acc[7]=fmaf(a1.w,xv[q],acc[7]);
    }
  }
  for (; i<deg; i+=2){                    // rare tail: deg > ECAP, recompute
    int sn = csr_src[off+i];
    float xv = b2f(xb[(size_t)sn*IN_DIM + d]);
    #pragma unroll
    for (int hh=0;hh<H_;hh++){
      float sc = elr[sn*16+hh] + elr[n*16+8+hh];
      sc = sc>0.f? sc : 0.2f*sc;
      float a = __expf(sc - s_m[w][hh]) * s_is[w][hh];
      acc[hh]=fmaf(a,xv,acc[hh]);
    }
  }
  #pragma unroll
  for (int hh=0;hh<H_;hh++)
    acc[hh] += __shfl_xor(acc[hh],32,64);
  if (hw==0){
    #pragma unroll
    for (int hh=0;hh<H_;hh++) s_hg[w][d*9+hh] = acc[hh];
  }
  __syncthreads();

  // ---- epilogue (column-split): wave w computes cols [w*64, w*64+64) for ALL 4 nodes ----
  int col = w*64 + lane;
  int hcol = col>>5;
  float a0=0.f, a1=0.f, a2=0.f, a3=0.f;
  #pragma unroll
  for (int kb=0;kb<4;kb++){
    u16x8 wv8 = *(const u16x8*)(W0t + ((size_t)(kb*HD + col)<<3));
    #pragma unroll
    for (int q=0;q<8;q++){
      float wv = b2f(wv8[q]);
      int k = kb*8+q;
      a0 = fmaf(s_hg[0][k*9+hcol], wv, a0);
      a1 = fmaf(s_hg[1][k*9+hcol], wv, a1);
      a2 = fmaf(s_hg[2][k*9+hcol], wv, a2);
      a3 = fmaf(s_hg[3][k*9+hcol], wv, a3);
    }
  }
  float bb = b0[col];
  int n0 = blockIdx.x*4;
  h1b[(size_t)(n0+0)*HD+col] = f2b(fmaxf(a0+bb,0.f));
  h1b[(size_t)(n0+1)*HD+col] = f2b(fmaxf(a1+bb,0.f));
  h1b[(size_t)(n0+2)*HD+col] = f2b(fmaxf(a2+bb,0.f));
  h1b[(size_t)(n0+3)*HD+col] = f2b(fmaxf(a3+bb,0.f));
}

// ---------------- feat1 = h1b @ [W1 | Wa1] via MFMA; 32 rows/wave ----------------

__global__ __launch_bounds__(256) void k_gemm1_mfma(const unsigned short* __restrict__ h1b,
    const unsigned short* __restrict__ Wp, unsigned short* __restrict__ featb,
    float* __restrict__ elr1){
  int wv = threadIdx.x>>6, lane = threadIdx.x&63;
  int rb = blockIdx.x*128 + wv*32;
  int ar0 = rb + (lane&15);
  int ar1 = ar0 + 16;
  if (ar0 >= N_NODES) ar0 = N_NODES-1;   // clamp reads; writes guarded below
  if (ar1 >= N_NODES) ar1 = N_NODES-1;
  int kgrp = lane>>4;
  f32x4 acc0[NT], acc1[NT];
  #pragma unroll
  for (int nt=0;nt<NT;nt++){ acc0[nt]=(f32x4){0.f,0.f,0.f,0.f}; acc1[nt]=(f32x4){0.f,0.f,0.f,0.f}; }
  const unsigned short* ap0 = h1b + (size_t)ar0*HD + kgrp*8;
  const unsigned short* ap1 = h1b + (size_t)ar1*HD + kgrp*8;
  #pragma unroll
  for (int ks=0; ks<8; ks++){
    bf16x8 a0 = *(const bf16x8*)(ap0 + ks*32);
    bf16x8 a1 = *(const bf16x8*)(ap1 + ks*32);
    #pragma unroll
    for (int nt=0; nt<NT; nt++){
      bf16x8 b = *(const bf16x8*)(Wp + (((ks*NT+nt)*64+lane)<<3));
      acc0[nt] = __builtin_amdgcn_mfma_f32_16x16x32_bf16(a0, b, acc0[nt], 0, 0, 0);
      acc1[nt] = __builtin_amdgcn_mfma_f32_16x16x32_bf16(a1, b, acc1[nt], 0, 0, 0);
    }
  }
  int col = lane&15;
  int rb0 = rb + (lane>>4)*4;
  int rb1 = rb0 + 16;
  #pragma unroll
  for (int nt=0;nt<16;nt++){
    #pragma unroll
    for (int r=0;r<4;r++){
      int row0 = rb0+r, row1 = rb1+r;
      if (row0<N_NODES) featb[(size_t)row0*HD + nt*16+col] = f2b(acc0[nt][r]);
      if (row1<N_NODES) featb[(size_t)row1*HD + nt*16+col] = f2b(acc1[nt][r]);
    }
  }
  #pragma unroll
  for (int r=0;r<4;r++){
    int row0 = rb0+r, row1 = rb1+r;
    if (row0<N_NODES) elr1[(size_t)row0*16 + col] = acc0[16][r];
    if (row1<N_NODES) elr1[(size_t)row1*16 + col] = acc1[16][r];
  }
}

// ---------------- layer-1 agg, HEAD-PAIR SPLIT ----------------
// bid = g*4+hp: head pair hp -> XCDs {hp, hp+4}; per-XCD featb working set = 6.4 MB.
// wave = node; phase A: hh=lane>>5 (head in pair), sub=lane&31.
// phase B: half-wave per edge, lane covers 2 cols (4B) of the 64-col chunk.
// epilogue: shfl combine + atomicAdd partial (out zeroed by memset).

__global__ __launch_bounds__(256) void k_agg1(const int* __restrict__ offs, const int* __restrict__ csr_src,
   const int* __restrict__ csr_eid, const unsigned short* __restrict__ featb, const float* __restrict__ elr,
   const float* __restrict__ bias, float* __restrict__ out, float* __restrict__ alpha_out){
  __shared__ float s_al[4][ECAP][2];
  __shared__ int   s_sn[4][ECAP];
  __shared__ float s_m[4][2], s_is[4][2];
  int bid = blockIdx.x;
  int hp = bid & 3;
  int g  = bid >> 2;
  int w = threadIdx.x>>6, lane = threadIdx.x&63;
  int n = g*4 + w;
  int hh = lane>>5, sub = lane&31;
  int h  = hp*2 + hh;
  int off = offs[n], deg = offs[n+1]-off;
  float er_n = elr[n*16 + 8 + h];

  // ---- phase A ----
  float m=-1e30f, s=0.f;
  for (int i=sub; i<deg; i+=32){
    int sn = csr_src[off+i];
    float sc = elr[sn*16+h] + er_n;
    sc = sc>0.f? sc : 0.2f*sc;
    if (i<ECAP){ s_al[w][i][hh]=sc; if (hh==0) s_sn[w][i]=sn; }
    float mn = fmaxf(m,sc);
    s = s*__expf(m-mn) + __expf(sc-mn);
    m = mn;
  }
  #pragma unroll
  for (int o=16;o>=1;o>>=1){
    float m2=__shfl_xor(m,o,64), s2=__shfl_xor(s,o,64);
    float mn=fmaxf(m,m2);
    s = s*__expf(m-mn) + s2*__expf(m2-mn);
    m = mn;
  }
  float inv_s = (s>0.f)? 1.f/s : 0.f;
  if (sub==0){ s_m[w][hh]=m; s_is[w][hh]=inv_s; }
  int dcap = deg<ECAP? deg:ECAP;
  int dcap_pad = (dcap+15)&~15;
  __syncthreads();
  for (int i=sub; i<dcap; i+=32){
    float a = __expf(s_al[w][i][hh]-m)*inv_s;
    s_al[w][i][hh] = a;
    alpha_out[(size_t)csr_eid[off+i]*H_ + h] = a;
  }
  for (int i=dcap+lane; i<dcap_pad; i+=64){
    s_sn[w][i]=0; s_al[w][i][0]=0.f; s_al[w][i][1]=0.f;
  }
  __syncthreads();

  // ---- phase B: 16-edge chunks, half-wave per edge, 4B (2 cols) per lane ----
  int cl = lane&31;
  int hd = cl>>4;                    // head within pair owning my cols
  int coff = hp*64 + cl*2;           // global featb col of my 2 cols
  int hw = lane>>5;
  float acc0=0.f, acc1=0.f;
  for (int i=0; i<dcap_pad; i+=16){
    float av[8]; unsigned int uu[8];
    #pragma unroll
    for (int q=0;q<8;q++){
      int e = i + 2*q + hw;
      int sn = s_sn[w][e];
      av[q] = s_al[w][e][hd];
      uu[q] = *(const unsigned int*)&featb[(size_t)sn*HD + coff];
    }
    #pragma unroll
    for (int q=0;q<8;q++){
      acc0 = fmaf(av[q], b2f((unsigned short)(uu[q]&0xffffu)), acc0);
      acc1 = fmaf(av[q], b2f((unsigned short)(uu[q]>>16)), acc1);
    }
  }
  for (int i=ECAP; i<deg; ++i){       // rare tail: deg > ECAP
    int p = off+i;
    int sn = csr_src[p];
    int ht = hp*2 + hd;
    float sc = elr[sn*16+ht] + elr[n*16+8+ht];
    sc = sc>0.f? sc : 0.2f*sc;
    float a = __expf(sc - s_m[w][hd]) * s_is[w][hd];
    unsigned int u = *(const unsigned int*)&featb[(size_t)sn*HD + coff];
    acc0 = fmaf(a, b2f((unsigned short)(u&0xffffu)), acc0);
    acc1 = fmaf(a, b2f((unsigned short)(u>>16)), acc1);
    if (hw==0 && (cl==0 || cl==16)) alpha_out[(size_t)csr_eid[p]*H_ + ht] = a;
  }

  // combine edge-parity halves, then the two heads (partner lane cl^16 has same d)
  acc0 += __shfl_xor(acc0,32,64);
  acc1 += __shfl_xor(acc1,32,64);
  acc0 += __shfl_xor(acc0,16,64);
  acc1 += __shfl_xor(acc1,16,64);
  if (lane<16){
    int d0 = lane*2;
    float c0v = 0.125f*(acc0 + bias[hp*64+d0]   + bias[hp*64+32+d0]);
    float c1v = 0.125f*(acc1 + bias[hp*64+d0+1] + bias[hp*64+32+d0+1]);
    atomicAdd(&out[(size_t)n*D_ + d0],   c0v);
    atomicAdd(&out[(size_t)n*D_ + d0+1], c1v);
  }
}

// ---------------- launcher ----------------

extern "C" void kernel_launch(void* const* d_in, const int* in_sizes, int n_in,
                              void* d_out, int out_size, void* d_ws, size_t ws_size,
                              hipStream_t stream){
  const float* h   = (const float*)d_in[0];
  const int*   src = (const int*)d_in[1];
  const int*   dst = (const int*)d_in[2];
  const float* W0  = (const float*)d_in[3];
  const float* al0 = (const float*)d_in[4];
  const float* ar0 = (const float*)d_in[5];
  const float* b0  = (const float*)d_in[6];
  const float* W1  = (const float*)d_in[7];
  const float* al1 = (const float*)d_in[8];
  const float* ar1 = (const float*)d_in[9];
  const float* b1  = (const float*)d_in[10];
  float* out_final = (float*)d_out;
  float* alpha_out = (float*)d_out + (size_t)N_NODES*D_;

  char* wsp = (char*)d_ws;
  auto alloc=[&](size_t bytes)->char*{ char* p=wsp; wsp += (bytes+255)&~size_t(255); return p; };
  int*   deg     = (int*)alloc((size_t)N_NODES*4);
  int*   offs    = (int*)alloc((size_t)(N_NODES+1)*4);
  int*   cursor  = (int*)alloc((size_t)N_NODES*4);
  int*   bsums   = (int*)alloc(1024);
  int*   csr_src = (int*)alloc((size_t)N_EDGES*4);
  int*   csr_eid = (int*)alloc((size_t)N_EDGES*4);
  unsigned short* featb = (unsigned short*)alloc((size_t)N_NODES*HD*2);
  unsigned short* h1b   = (unsigned short*)alloc((size_t)N_NODES*HD*2);
  unsigned short* xb    = (unsigned short*)alloc((size_t)N_NODES*IN_DIM*2);
  float* elr0    = (float*)alloc((size_t)N_NODES*16*4);
  float* elr1    = (float*)alloc((size_t)N_NODES*16*4);
  float* Wa0     = (float*)alloc((size_t)IN_DIM*16*4);
  float* Wa1     = (float*)alloc((size_t)HD*16*4);
  unsigned short* Wp  = (unsigned short*)alloc((size_t)8*NT*64*8*2);
  unsigned short* W0t = (unsigned short*)alloc((size_t)8192*2);

  hipMemsetAsync(deg, 0, (size_t)N_NODES*4, stream);
  hipMemsetAsync(out_final, 0, (size_t)N_NODES*D_*4, stream);   // agg1 accumulates via atomics
  int eb = (N_EDGES+255)/256;
  int nbchunks = (N_NODES+255)/256;
  k_hist       <<<eb,      256,0,stream>>>(dst, deg);
  k_block_sums <<<nbchunks,256,0,stream>>>(deg, bsums);
  k_scan_bsums <<<1,       64, 0,stream>>>(bsums, nbchunks);
  k_scan_chunks<<<nbchunks,256,0,stream>>>(deg, bsums, offs, cursor);
  k_scatter    <<<eb,      256,0,stream>>>(src, dst, cursor, csr_src, csr_eid);

  k_prep<IN_DIM><<<1,256,0,stream>>>(W0, al0, ar0, Wa0);
  k_prep<HD>    <<<8,256,0,stream>>>(W1, al1, ar1, Wa1);
  k_pack_w      <<<(8*NT*64*8+255)/256,256,0,stream>>>(W1, Wa1, Wp);
  k_pack_w0     <<<32,256,0,stream>>>(W0, W0t);

  k_el0       <<<N_NODES/16,256,0,stream>>>(h, Wa0, elr0, xb);
  k_agg0f     <<<N_NODES/4, 256,0,stream>>>(offs, csr_src, xb, elr0, W0t, b0, h1b);
  k_gemm1_mfma<<<(N_NODES+127)/128,256,0,stream>>>(h1b, Wp, featb, elr1);
  k_agg1      <<<N_NODES, 256,0,stream>>>(offs, csr_src, csr_eid, featb, elr1, b1, out_final, alpha_out);
}